// Round 7
// baseline (596.596 us; speedup 1.0000x reference)
//
#include <hip/hip_runtime.h>

#define EPS_F 0.1f
#define A_F 100.0f
#define NUMNEG_F 10.0f
#define EXP_EPS 1.1051709f   // e^0.1; gate: dist<EPS  <=>  (-inner + s) < e^EPS
#define CAP 64               // per-node adjacency capacity (mean deg 20, Poisson)
#define BATCH 16

// ---- K1: bucketed adjacency fill (int atomics only) ----
__global__ __launch_bounds__(256) void bucket_fill(
    const int* __restrict__ u_idx, const int* __restrict__ v_idx,
    int* __restrict__ counts, int* __restrict__ entries, int E)
{
    const int i = blockIdx.x * blockDim.x + threadIdx.x;
    if (i >= 2 * E) return;
    int n, other;
    if (i < E) { n = u_idx[i];     other = v_idx[i]; }
    else       { n = v_idx[i - E]; other = u_idx[i - E]; }
    const int slot = atomicAdd(&counts[n], 1);
    if (slot < CAP) entries[n * CAP + slot] = other;
}

// ---- K2: one wave per node; gather neighbors, accumulate grad row in regs,
//          ONE plain 256B store per node. No float atomics anywhere. ----
__global__ __launch_bounds__(256) void node_kernel(
    const float* __restrict__ x,
    const int* __restrict__ counts,
    const int* __restrict__ entries,
    float* __restrict__ out,          // out[0]=energy, out+1 = grad
    float* __restrict__ block_energy, // one float per block
    int N)
{
    const int lane = threadIdx.x & 63;
    const int wib  = threadIdx.x >> 6;
    const int wave = (blockIdx.x * blockDim.x + threadIdx.x) >> 6;
    const int nwaves = (gridDim.x * blockDim.x) >> 6;
    const float sign = (lane == 0) ? -1.0f : 1.0f;  // Minkowski J
    float* __restrict__ grad = out + 1;

    float eacc = 0.0f;  // wave-uniform; each edge appears twice in adjacency

    for (int u = wave; u < N; u += nwaves) {
        int deg = __builtin_amdgcn_readfirstlane(counts[u]);
        if (deg > CAP) deg = CAP;
        const float xu = x[(size_t)u * 64 + lane];
        const int myv = (lane < deg) ? entries[u * CAP + lane] : 0;  // coalesced
        float gacc = 0.0f;

        for (int k0 = 0; k0 < deg; k0 += BATCH) {
            const int bn = min(BATCH, deg - k0);
            int vs[BATCH]; float xv[BATCH], p[BATCH];

            // broadcast neighbor ids, issue all gathers back-to-back (MLP)
            #pragma unroll
            for (int k = 0; k < BATCH; k++) {
                if (k < bn) {
                    vs[k] = __builtin_amdgcn_readlane(myv, k0 + k);
                    xv[k] = x[(size_t)vs[k] * 64 + lane];
                }
            }
            #pragma unroll
            for (int k = 0; k < BATCH; k++)
                p[k] = (k < bn) ? xu * xv[k] * sign : 0.0f;

            // independent butterfly chains, level-interleaved
            #pragma unroll
            for (int off = 32; off >= 1; off >>= 1) {
                #pragma unroll
                for (int k = 0; k < BATCH; k++)
                    p[k] += __shfl_xor(p[k], off, 64);
            }

            #pragma unroll
            for (int k = 0; k < BATCH; k++) {
                if (k < bn) {
                    const float inner = fminf(p[k], -1.0f - 1e-7f);
                    const float s = sqrtf(inner * inner - 1.0f);
                    const float t = -inner + s;          // dist = log(t)
                    if (t < EXP_EPS) {                   // wave-uniform branch
                        const float dist = __logf(t);
                        const float delta = EPS_F - dist;
                        eacc += delta * delta;
                        const float factor = -(A_F / NUMNEG_F) * delta / (s + 1e-9f);
                        gacc = fmaf(factor, xv[k], gacc);
                    }
                }
            }
        }
        // grad_u[lane] = sign * sum_e factor_e * xv_e[lane]   (plain store)
        grad[(size_t)u * 64 + lane] = gacc * sign;
    }

    __shared__ float se[4];
    if (lane == 0) se[wib] = eacc;
    __syncthreads();
    if (threadIdx.x == 0)
        block_energy[blockIdx.x] = se[0] + se[1] + se[2] + se[3];
}

// ---- K3: final energy reduce (plain store to out[0]) ----
__global__ __launch_bounds__(256) void energy_reduce_kernel(
    const float* __restrict__ block_energy, float* __restrict__ out, int n)
{
    const int lane = threadIdx.x & 63;
    const int wib  = threadIdx.x >> 6;
    float s = 0.0f;
    for (int i = threadIdx.x; i < n; i += 256) s += block_energy[i];
    #pragma unroll
    for (int off = 32; off >= 1; off >>= 1) s += __shfl_xor(s, off, 64);
    __shared__ float se[4];
    if (lane == 0) se[wib] = s;
    __syncthreads();
    if (threadIdx.x == 0)
        // each edge counted twice in adjacency -> extra factor 1/2
        out[0] = (se[0] + se[1] + se[2] + se[3]) * (0.25f * A_F / NUMNEG_F);
}

extern "C" void kernel_launch(void* const* d_in, const int* in_sizes, int n_in,
                              void* d_out, int out_size, void* d_ws, size_t ws_size,
                              hipStream_t stream) {
    const float* x     = (const float*)d_in[0];
    const int*   u_idx = (const int*)d_in[1];
    const int*   v_idx = (const int*)d_in[2];
    float* out = (float*)d_out;
    const int E = in_sizes[1];
    const int N = in_sizes[0] / 64;

    // ws layout
    char* ws = (char*)d_ws;
    int*   counts       = (int*)ws;                          // N ints (~400 KB)
    int*   entries      = (int*)(ws + (1 << 20));            // N*CAP ints (~25.6 MB)
    float* block_energy = (float*)(ws + (1 << 20) + (size_t)N * CAP * 4 + (1 << 20));

    // counts must start at zero every call (ws is re-poisoned)
    hipMemsetAsync(counts, 0, (size_t)N * sizeof(int), stream);

    bucket_fill<<<(2 * E + 255) / 256, 256, 0, stream>>>(u_idx, v_idx, counts, entries, E);

    const int blocks = (N + 3) / 4;   // 4 waves/block, one wave per node
    node_kernel<<<blocks, 256, 0, stream>>>(x, counts, entries, out, block_energy, N);

    energy_reduce_kernel<<<1, 256, 0, stream>>>(block_energy, out, blocks);
}

// Round 8
// 355.225 us; speedup vs baseline: 1.6795x; 1.6795x over previous
//
#include <hip/hip_runtime.h>

#define EPS_F 0.1f
#define A_F 100.0f
#define NUMNEG_F 10.0f
#define EXP_EPS 1.1051709f   // e^0.1; gate: dist<EPS  <=>  (-inner + s) < e^EPS
#define CAP 64               // per-node capacity; one-sided deg ~ Poisson(10)
#define BATCH 16
#define NBLOCKS 4096

// ---- K1: ONE-SIDED bucket fill: edge e listed under u_idx[e] only ----
__global__ __launch_bounds__(256) void bucket_fill(
    const int* __restrict__ u_idx, const int* __restrict__ v_idx,
    int* __restrict__ counts, int* __restrict__ entries, int E)
{
    const int i = blockIdx.x * blockDim.x + threadIdx.x;
    if (i >= E) return;
    const int u = u_idx[i];
    const int slot = atomicAdd(&counts[u], 1);
    if (slot < CAP) entries[u * CAP + slot] = v_idx[i];
}

// ---- K2: one wave per node u; each edge handled ONCE.
//      grad_u accumulated in registers (one atomic row-add per node),
//      grad_v scattered with coalesced f32 atomics (one per active edge). ----
__global__ __launch_bounds__(256) void node_kernel(
    const float* __restrict__ x,
    const int* __restrict__ counts,
    const int* __restrict__ entries,
    float* __restrict__ out,          // out[0]=energy, out+1 = grad
    float* __restrict__ block_energy, // one float per block
    int N)
{
    const int lane = threadIdx.x & 63;
    const int wib  = threadIdx.x >> 6;
    const int wave = (blockIdx.x * blockDim.x + threadIdx.x) >> 6;
    const int nwaves = (gridDim.x * blockDim.x) >> 6;
    const float sign = (lane == 0) ? -1.0f : 1.0f;  // Minkowski J
    float* __restrict__ grad = out + 1;

    float eacc = 0.0f;  // each edge counted once

    // prefetch first node's adjacency
    int u = wave;
    int deg = 0, myv = 0;
    if (u < N) {
        deg = counts[u];
        myv = entries[u * CAP + lane];   // unconditional; masked by deg later
    }

    while (u < N) {
        const int deg_c = min(deg, CAP);
        const int myv_c = myv;
        const float xu = x[(size_t)u * 64 + lane];

        // prefetch next node's adjacency (overlaps with this node's gathers)
        const int un = u + nwaves;
        if (un < N) {
            deg = counts[un];
            myv = entries[un * CAP + lane];
        }

        float gacc = 0.0f;
        for (int k0 = 0; k0 < deg_c; k0 += BATCH) {
            const int bn = min(BATCH, deg_c - k0);
            int vs[BATCH]; float xv[BATCH], p[BATCH];

            // broadcast neighbor ids, issue gathers back-to-back (MLP)
            #pragma unroll
            for (int k = 0; k < BATCH; k++) {
                if (k < bn) {
                    vs[k] = __builtin_amdgcn_readlane(myv_c, k0 + k);
                    xv[k] = x[(size_t)vs[k] * 64 + lane];
                }
            }
            #pragma unroll
            for (int k = 0; k < BATCH; k++)
                p[k] = (k < bn) ? xu * xv[k] * sign : 0.0f;

            // independent butterfly chains, level-interleaved
            #pragma unroll
            for (int off = 32; off >= 1; off >>= 1) {
                #pragma unroll
                for (int k = 0; k < BATCH; k++)
                    if (k < bn) p[k] += __shfl_xor(p[k], off, 64);
            }

            #pragma unroll
            for (int k = 0; k < BATCH; k++) {
                if (k < bn) {
                    const float inner = fminf(p[k], -1.0f - 1e-7f);
                    const float s = sqrtf(inner * inner - 1.0f);
                    const float t = -inner + s;          // dist = log(t)
                    if (t < EXP_EPS) {                   // wave-uniform branch
                        const float dist = __logf(t);
                        const float delta = EPS_F - dist;
                        eacc += delta * delta;
                        const float factor = -(A_F / NUMNEG_F) * delta / (s + 1e-9f);
                        // grad_v: coalesced 256B atomic row-add
                        unsafeAtomicAdd(&grad[(size_t)vs[k] * 64 + lane],
                                        factor * xu * sign);
                        // grad_u: accumulate in register
                        gacc = fmaf(factor, xv[k], gacc);
                    }
                }
            }
        }
        if (deg_c > 0)
            unsafeAtomicAdd(&grad[(size_t)u * 64 + lane], gacc * sign);
        u = un;
    }

    __shared__ float se[4];
    if (lane == 0) se[wib] = eacc;
    __syncthreads();
    if (threadIdx.x == 0)
        block_energy[blockIdx.x] = se[0] + se[1] + se[2] + se[3];
}

// ---- K3: final energy reduce (plain store to out[0]) ----
__global__ __launch_bounds__(256) void energy_reduce_kernel(
    const float* __restrict__ block_energy, float* __restrict__ out, int n)
{
    const int lane = threadIdx.x & 63;
    const int wib  = threadIdx.x >> 6;
    float s = 0.0f;
    for (int i = threadIdx.x; i < n; i += 256) s += block_energy[i];
    #pragma unroll
    for (int off = 32; off >= 1; off >>= 1) s += __shfl_xor(s, off, 64);
    __shared__ float se[4];
    if (lane == 0) se[wib] = s;
    __syncthreads();
    if (threadIdx.x == 0)
        out[0] = (se[0] + se[1] + se[2] + se[3]) * (0.5f * A_F / NUMNEG_F);
}

extern "C" void kernel_launch(void* const* d_in, const int* in_sizes, int n_in,
                              void* d_out, int out_size, void* d_ws, size_t ws_size,
                              hipStream_t stream) {
    const float* x     = (const float*)d_in[0];
    const int*   u_idx = (const int*)d_in[1];
    const int*   v_idx = (const int*)d_in[2];
    float* out = (float*)d_out;
    const int E = in_sizes[1];
    const int N = in_sizes[0] / 64;

    // ws layout
    char* ws = (char*)d_ws;
    int*   counts       = (int*)ws;                          // N ints
    int*   entries      = (int*)(ws + (1 << 20));            // N*CAP ints (~25.6 MB)
    float* block_energy = (float*)(ws + (1 << 20) + (size_t)N * CAP * 4 + (1 << 20));

    // grad must start at zero (atomic accumulation); counts must start at zero
    hipMemsetAsync(d_out, 0, (size_t)out_size * sizeof(float), stream);
    hipMemsetAsync(counts, 0, (size_t)N * sizeof(int), stream);

    bucket_fill<<<(E + 255) / 256, 256, 0, stream>>>(u_idx, v_idx, counts, entries, E);

    node_kernel<<<NBLOCKS, 256, 0, stream>>>(x, counts, entries, out, block_energy, N);

    energy_reduce_kernel<<<1, 256, 0, stream>>>(block_energy, out, NBLOCKS);
}